// Round 8
// baseline (616.346 us; speedup 1.0000x reference)
//
#include <hip/hip_runtime.h>
#include <cstdint>

#define BATCH 8
#define NPTS  4096
#define MPTS  1024
#define DIM   64
#define SA_BLOCKS 128  // static-assembly blocks riding along with fps

typedef float v2f __attribute__((ext_vector_type(2)));
typedef unsigned long long u64;
typedef unsigned int u32;

// Pack (f32 distance bits, aux) into a double whose VALUE ordering equals the
// u64 bit-pattern ordering: hi word = f32 bits of a non-negative float
// (<= FLT_MAX bits 0x7F7FFFFF -> f64 exponent <= 2039, sign 0 -> positive
// finite double). So v_max_f64 / v_min_f64 (1 inst each) give exact u64
// max/min — replacing the 3-inst v_cmp_u64+2*cndmask sequence.
__device__ __forceinline__ double mk_key(float m, u32 aux) {
  const u64 k = ((u64)__float_as_uint(m) << 32) | (u64)aux;
  return __longlong_as_double((long long)k);
}
__device__ __forceinline__ u32 key_lo(double d) {
  return (u32)(u64)__double_as_longlong(d);
}

// One DPP step of a 64-lane f64-key max reduction. bound_ctrl=true -> invalid
// source lanes read 0.0, the identity for max of positive keys.
#define WAVE_MAX_F64_STEP(x, ctrl)                                                    \
  {                                                                                   \
    const u64 xu_ = (u64)__double_as_longlong(x);                                     \
    const int lo_ = __builtin_amdgcn_update_dpp(0, (int)(u32)xu_, (ctrl), 0xf, 0xf, true);  \
    const int hi_ = __builtin_amdgcn_update_dpp(0, (int)(u32)(xu_ >> 32), (ctrl), 0xf, 0xf, true); \
    const double y_ = __longlong_as_double((long long)(((u64)(u32)hi_ << 32) | (u64)(u32)lo_)); \
    (x) = fmax((x), y_);                                                              \
  }

// ------------- Kernel 1: FPS + overlapped static output assembly -----------
// Grid-union fuse (R7-verified: absorbs ~15MB static output traffic in the
// FPS shadow at zero duration cost): blocks 0..7 run FPS on 8 CUs; blocks
// 8..135 write out[:,0..66]=[x|pos], the zeros output, and the batch output.
//
// FPS core: R1 structure (barrier/DPP/publish/combine identical), with an
// R8 local-reduce swap: the 16->1 per-thread key reduce (16 mk_key pair
// moves + 15 v_max_f64, ~120-180cy issue) is replaced by a packed f32 value
// tree (7 v_pk_max_f32 + 1 v_max_f32) + equality-descent for the slot index
// (verified correct in R3's passing run) + ONE mk_key. Slot mapping permuted
// at load (slot(g,h) <-> idx t+(h*8+g)*256) so leftmost-descent == smallest
// global idx — exact np.argmax tie semantics.
// Locked lessons: R2 more waves -19%; R3 replacing the WAVE reduce -9%;
// R4 speculative scattered gather -25%. Wave reduce stays f64-DPP.
__global__ __launch_bounds__(256) void fps_static_kernel(
    const float* __restrict__ pos, const float* __restrict__ x,
    int* __restrict__ gidx, float* __restrict__ out) {
#pragma clang fp contract(off)
  const int t = threadIdx.x;

  if (blockIdx.x >= BATCH) {
    // ---- static assembly: 256 rows per block, wave-coalesced ----
    const int sb = blockIdx.x - BATCH;
    const int wid = t >> 6;
    const int lane = t & 63;
    const int rowbase = sb * 256;
#pragma unroll 4
    for (int n = 0; n < 64; ++n) {
      const int row = rowbase + wid * 64 + n;
      float* o = out + (size_t)row * 134;
      o[lane] = x[(size_t)row * DIM + lane];     // coalesced 64-float row
      if (lane < 3) o[64 + lane] = pos[3 * row + lane];
    }
    float* o2 = out + (size_t)BATCH * NPTS * 134 + (size_t)rowbase * 3;
    for (int q = t; q < 768; q += 256) o2[q] = 0.0f;  // zeros output [B*N,3]
    float* o3 = out + (size_t)BATCH * NPTS * 134 + (size_t)BATCH * NPTS * 3;
    o3[rowbase + t] = (float)((rowbase + t) >> 12);   // batch id = row/NPTS
    return;
  }

  const int b = blockIdx.x;
  const float* p = pos + (size_t)b * NPTS * 3;

  __shared__ float4 sp[NPTS];
  __shared__ double red[2][4];

  v2f px[8], py[8], pz[8], mind[8];
#pragma unroll
  for (int k = 0; k < 16; ++k) {
    const int i = t + k * 256;          // point index
    const int g = k & 7, h = k >> 3;    // slot (g,h) <-> idx t + (h*8+g)*256
    const float a = p[3 * i + 0];
    const float c = p[3 * i + 1];
    const float d = p[3 * i + 2];
    sp[i] = make_float4(a, c, d, 0.0f);
    px[g][h] = a;
    py[g][h] = c;
    pz[g][h] = d;
    mind[g][h] = 3.402823466e+38f;  // finfo(float32).max
  }
  __syncthreads();

  float4 w = sp[0];
  float lx = w.x, ly = w.y, lz = w.z;

  int h0 = 0, h1 = 0, h2 = 0, h3 = 0;
  const int it1 = t + 256, it2 = t + 512, it3 = t + 768;
  const u32 nott = ~(u32)t;

  for (int it = 1; it < MPTS; ++it) {
    const v2f vlx = {lx, lx}, vly = {ly, ly}, vlz = {lz, lz};
#pragma unroll
    for (int g = 0; g < 8; ++g) {
      // strict fp32, no contraction: ((dx*dx + dy*dy) + dz*dz), per element
      const v2f dx = px[g] - vlx;
      const v2f dy = py[g] - vly;
      const v2f dz = pz[g] - vlz;
      const v2f d = (dx * dx + dy * dy) + dz * dz;
      mind[g] = __builtin_elementwise_min(mind[g], d);
    }

    // ---- local value tree: 7 packed f32 max + 1 scalar max ----
    const v2f t0 = __builtin_elementwise_max(mind[0], mind[1]);  // g{0,1}
    const v2f t1 = __builtin_elementwise_max(mind[2], mind[3]);  // g{2,3}
    const v2f t2 = __builtin_elementwise_max(mind[4], mind[5]);  // g{4,5}
    const v2f t3 = __builtin_elementwise_max(mind[6], mind[7]);  // g{6,7}
    const v2f u0 = __builtin_elementwise_max(t0, t1);            // g{0..3}
    const v2f u1 = __builtin_elementwise_max(t2, t3);            // g{4..7}
    const v2f vv = __builtin_elementwise_max(u0, u1);            // per-h max
    const float m16 = fmaxf(vv[0], vv[1]);

    // ---- equality-descent (leftmost in (h,g) order == smallest idx) ----
    const bool eH = (vv[0] == m16);            // h=0 wins (smaller idx block)
    const float u0h = eH ? u0[0] : u0[1];
    const bool e2 = (u0h == m16);              // g in 0..3
    const float t0h = eH ? t0[0] : t0[1];
    const float t2h = eH ? t2[0] : t2[1];
    const float tLh = e2 ? t0h : t2h;
    const bool e1 = (tLh == m16);              // g in {0,1} / {4,5}
    const float m0h = eH ? mind[0][0] : mind[0][1];
    const float m2h = eH ? mind[2][0] : mind[2][1];
    const float m4h = eH ? mind[4][0] : mind[4][1];
    const float m6h = eH ? mind[6][0] : mind[6][1];
    const float pA = e1 ? m0h : m2h;
    const float pB = e1 ? m4h : m6h;
    const float vL = e2 ? pA : pB;
    const bool e0 = (vL == m16);               // g even
    // idx = t + (h*2048 + g*256); ~(t+off) = ~t - off
    const u32 off = (eH ? 0u : 2048u) + (e2 ? 0u : 1024u) +
                    (e1 ? 0u : 512u) + (e0 ? 0u : 256u);
    const u32 myc = nott - off;                // ~idx: max -> smallest idx

    // ---- ONE key; wave reduce identical to R1 ----
    double best = mk_key(m16, myc);
    WAVE_MAX_F64_STEP(best, 0x111);  // row_shr:1
    WAVE_MAX_F64_STEP(best, 0x112);  // row_shr:2
    WAVE_MAX_F64_STEP(best, 0x114);  // row_shr:4
    WAVE_MAX_F64_STEP(best, 0x118);  // row_shr:8
    WAVE_MAX_F64_STEP(best, 0x142);  // row_bcast:15
    WAVE_MAX_F64_STEP(best, 0x143);  // row_bcast:31

    const int buf = it & 1;  // double-buffered slots: 1 barrier/iter
    if ((t & 63) == 63) red[buf][t >> 6] = best;
    __syncthreads();

    const double c = fmax(fmax(red[buf][0], red[buf][1]),
                          fmax(red[buf][2], red[buf][3]));
    const u32 widx = ~key_lo(c);  // low word = ~idx

    w = sp[widx];  // broadcast read (same address all lanes)
    lx = w.x; ly = w.y; lz = w.z;

    // off-critical-path register history update (4x cmp+cndmask, no VMEM)
    h0 = (it == t)   ? (int)widx : h0;
    h1 = (it == it1) ? (int)widx : h1;
    h2 = (it == it2) ? (int)widx : h2;
    h3 = (it == it3) ? (int)widx : h3;
  }

  // Epilogue: 4 coalesced stores per thread write all M winner indices.
  const int base = b * MPTS;
  const int goff = b * NPTS;
  gidx[base + t]       = goff + h0;
  gidx[base + 256 + t] = goff + h1;
  gidx[base + 512 + t] = goff + h2;
  gidx[base + 768 + t] = goff + h3;
}

// ------------- Kernel 2: k=1 NN + gather-dependent assembly ----------------
// B*32 blocks x 256 threads.
// Phase 1 (nn): 128 hr points/block, 2 threads per point splitting the
// M=1024 lr points in half; packed fp32; u64-key argmin (tie -> smallest j,
// matches np.argmin) via v_min_f64; pair combine via shfl_xor(1). nng stays
// in LDS (snn).
// Phase 2: only the FPS/NN-dependent columns remain (out[:,67..133] =
// [x[g] | pos[g]]) — the static columns are written by fps_static_kernel's
// rider blocks. Wave-coalesced: 32 rows per wave, lane-parallel.
__global__ __launch_bounds__(256) void nn_dyn_kernel(
    const float* __restrict__ x, const float* __restrict__ pos,
    const int* __restrict__ gidx, float* __restrict__ out) {
#pragma clang fp contract(off)
  const int b = blockIdx.x >> 5;
  const int chunk = blockIdx.x & 31;
  const int t = threadIdx.x;

  __shared__ float lrx[MPTS], lry[MPTS], lrz[MPTS];
  __shared__ int snn[128];

  for (int j = t; j < MPTS; j += 256) {
    const int g = gidx[b * MPTS + j];
    lrx[j] = pos[3 * g + 0];
    lry[j] = pos[3 * g + 1];
    lrz[j] = pos[3 * g + 2];
  }
  __syncthreads();

  const int r = t >> 1;      // local row 0..127
  const int half = t & 1;
  const int i = b * NPTS + chunk * 128 + r;  // global hr point index
  const float X = pos[3 * i + 0];
  const float Y = pos[3 * i + 1];
  const float Z = pos[3 * i + 2];
  const v2f vX = {X, X}, vY = {Y, Y}, vZ = {Z, Z};

  double best = __longlong_as_double(0x7FEFFFFFFFFFFFFFll);  // +DBL_MAX > all keys
  const int j0 = half * 512;
#pragma unroll 4
  for (int s = 0; s < 256; ++s) {
    const int j = j0 + 2 * s;
    const v2f qx = *(const v2f*)&lrx[j];
    const v2f qy = *(const v2f*)&lry[j];
    const v2f qz = *(const v2f*)&lrz[j];
    const v2f dx = vX - qx;
    const v2f dy = vY - qy;
    const v2f dz = vZ - qz;
    const v2f d = (dx * dx + dy * dy) + dz * dz;
    const double p0 = mk_key(d[0], (u32)j);
    const double p1 = mk_key(d[1], (u32)(j + 1));
    best = fmin(best, fmin(p0, p1));
  }
  // pair combine across the two halves (lanes differ only in bit 0)
  const u64 bu = (u64)__double_as_longlong(best);
  const u64 ou = ((u64)(u32)__shfl_xor((int)(bu >> 32), 1, 64) << 32) |
                 (u64)(u32)__shfl_xor((int)(u32)bu, 1, 64);
  best = fmin(best, __longlong_as_double((long long)ou));
  if (half == 0) snn[r] = gidx[b * MPTS + (int)key_lo(best)];
  __syncthreads();

  // ---- dependent assembly: wave-coalesced, 32 rows per wave ----
  const int wid = t >> 6;
  const int lane = t & 63;
  const int rowbase = b * NPTS + chunk * 128;
#pragma unroll 4
  for (int n = 0; n < 32; ++n) {
    const int rr = wid * 32 + n;
    const int ii = rowbase + rr;
    const int g = snn[rr];
    float* o = out + (size_t)ii * 134;
    o[67 + lane] = x[(size_t)g * DIM + lane];    // coalesced row gather
    if (lane < 3) o[131 + lane] = pos[3 * g + lane];
  }
}

// ---------------------------------------------------------------------------
extern "C" void kernel_launch(void* const* d_in, const int* in_sizes, int n_in,
                              void* d_out, int out_size, void* d_ws, size_t ws_size,
                              hipStream_t stream) {
  const float* x = (const float*)d_in[0];
  const float* pos = (const float*)d_in[1];

  int* gidx = (int*)d_ws;  // [B*M] global indices of sampled points

  float* out = (float*)d_out;

  fps_static_kernel<<<BATCH + SA_BLOCKS, 256, 0, stream>>>(pos, x, gidx, out);
  nn_dyn_kernel<<<BATCH * 32, 256, 0, stream>>>(x, pos, gidx, out);
}

// Round 9
// 564.763 us; speedup vs baseline: 1.0913x; 1.0913x over previous
//
#include <hip/hip_runtime.h>
#include <cstdint>

#define BATCH 8
#define NPTS  4096
#define MPTS  1024
#define DIM   64
#define SA_BLOCKS 128  // static-assembly blocks riding along with fps

typedef float v2f __attribute__((ext_vector_type(2)));
typedef unsigned long long u64;
typedef unsigned int u32;

// Pack (f32 distance bits, aux) into a double whose VALUE ordering equals the
// u64 bit-pattern ordering: hi word = f32 bits of a non-negative float
// (<= FLT_MAX bits 0x7F7FFFFF -> f64 exponent <= 2039, sign 0 -> positive
// finite double). So v_max_f64 / v_min_f64 (1 inst each) give exact u64
// max/min — replacing the 3-inst v_cmp_u64+2*cndmask sequence.
__device__ __forceinline__ double mk_key(float m, u32 aux) {
  const u64 k = ((u64)__float_as_uint(m) << 32) | (u64)aux;
  return __longlong_as_double((long long)k);
}
__device__ __forceinline__ u32 key_lo(double d) {
  return (u32)(u64)__double_as_longlong(d);
}

// One DPP step of a 64-lane f64-key max reduction. bound_ctrl=true -> invalid
// source lanes read 0.0, the identity for max of positive keys.
#define WAVE_MAX_F64_STEP(x, ctrl)                                                    \
  {                                                                                   \
    const u64 xu_ = (u64)__double_as_longlong(x);                                     \
    const int lo_ = __builtin_amdgcn_update_dpp(0, (int)(u32)xu_, (ctrl), 0xf, 0xf, true);  \
    const int hi_ = __builtin_amdgcn_update_dpp(0, (int)(u32)(xu_ >> 32), (ctrl), 0xf, 0xf, true); \
    const double y_ = __longlong_as_double((long long)(((u64)(u32)hi_ << 32) | (u64)(u32)lo_)); \
    (x) = fmax((x), y_);                                                              \
  }

// ------------- Kernel 1: FPS + overlapped static output assembly -----------
// Grid-union fuse (R7-verified: absorbs ~15MB static output traffic in the
// FPS shadow at zero duration cost): blocks 0..7 run FPS on 8 CUs; blocks
// 8..135 write out[:,0..66]=[x|pos], the zeros output, and the batch output.
//
// FPS core: EXACT R1 structure — the measured optimum (473-475 µs). 256
// threads (4 waves, 1/SIMD), 16 pts/thread as 8 float2 groups; u64-key
// argmax (tie -> smallest idx, matches np.argmax) via v_max_f64; 6-step DPP
// wave reduce; lane63 publish; 1 barrier/iter (double-buffered slots);
// 4-slot combine; winner coords via broadcast ds_read_b128; zero VMEM in
// the loop (winner history in registers, thread t owns iterations t+256k).
//
// Session map — all fps-loop restructurings REGRESSED (marginal serial inst
// ≈ 6cy, latency-chain-bound): R2 8 waves -19%; R3 f32 reduce + readlane
// -9%; R4 speculative gather + branchy publish -25%; R8 pk-value-tree +
// equality-descent -14%. Wins were removals only: R1 in-loop VMEM, R7
// kernel-2 serialization. Do not reshuffle the reduce.
__global__ __launch_bounds__(256) void fps_static_kernel(
    const float* __restrict__ pos, const float* __restrict__ x,
    int* __restrict__ gidx, float* __restrict__ out) {
#pragma clang fp contract(off)
  const int t = threadIdx.x;

  if (blockIdx.x >= BATCH) {
    // ---- static assembly: 256 rows per block, wave-coalesced ----
    const int sb = blockIdx.x - BATCH;
    const int wid = t >> 6;
    const int lane = t & 63;
    const int rowbase = sb * 256;
#pragma unroll 4
    for (int n = 0; n < 64; ++n) {
      const int row = rowbase + wid * 64 + n;
      float* o = out + (size_t)row * 134;
      o[lane] = x[(size_t)row * DIM + lane];     // coalesced 64-float row
      if (lane < 3) o[64 + lane] = pos[3 * row + lane];
    }
    float* o2 = out + (size_t)BATCH * NPTS * 134 + (size_t)rowbase * 3;
    for (int q = t; q < 768; q += 256) o2[q] = 0.0f;  // zeros output [B*N,3]
    float* o3 = out + (size_t)BATCH * NPTS * 134 + (size_t)BATCH * NPTS * 3;
    o3[rowbase + t] = (float)((rowbase + t) >> 12);   // batch id = row/NPTS
    return;
  }

  const int b = blockIdx.x;
  const float* p = pos + (size_t)b * NPTS * 3;

  __shared__ float4 sp[NPTS];
  __shared__ double red[2][4];

  v2f px[8], py[8], pz[8], mind[8];
#pragma unroll
  for (int k = 0; k < 16; ++k) {
    const int i = t + k * 256;
    const float a = p[3 * i + 0];
    const float c = p[3 * i + 1];
    const float d = p[3 * i + 2];
    sp[i] = make_float4(a, c, d, 0.0f);
    px[k >> 1][k & 1] = a;
    py[k >> 1][k & 1] = c;
    pz[k >> 1][k & 1] = d;
    mind[k >> 1][k & 1] = 3.402823466e+38f;  // finfo(float32).max
  }
  __syncthreads();

  float4 w = sp[0];
  float lx = w.x, ly = w.y, lz = w.z;

  int h0 = 0, h1 = 0, h2 = 0, h3 = 0;
  const int it1 = t + 256, it2 = t + 512, it3 = t + 768;

  for (int it = 1; it < MPTS; ++it) {
    const v2f vlx = {lx, lx}, vly = {ly, ly}, vlz = {lz, lz};
    double pg[8];
#pragma unroll
    for (int g = 0; g < 8; ++g) {
      // strict fp32, no contraction: ((dx*dx + dy*dy) + dz*dz), per element
      const v2f dx = px[g] - vlx;
      const v2f dy = py[g] - vly;
      const v2f dz = pz[g] - vlz;
      const v2f d = (dx * dx + dy * dy) + dz * dz;
      const v2f m = __builtin_elementwise_min(mind[g], d);
      mind[g] = m;
      const double p0 = mk_key(m[0], ~(u32)(t + (2 * g) * 256));      // hoisted consts
      const double p1 = mk_key(m[1], ~(u32)(t + (2 * g + 1) * 256));  // tie -> larger ~idx
      pg[g] = fmax(p0, p1);
    }
    // thread-local tree (all single v_max_f64)
    const double b0 = fmax(pg[0], pg[1]);
    const double b1 = fmax(pg[2], pg[3]);
    const double b2 = fmax(pg[4], pg[5]);
    const double b3 = fmax(pg[6], pg[7]);
    double best = fmax(fmax(b0, b1), fmax(b2, b3));

    // 64-lane wave max via DPP: rows (16) then cross-row bcasts; lane 63 final.
    WAVE_MAX_F64_STEP(best, 0x111);  // row_shr:1
    WAVE_MAX_F64_STEP(best, 0x112);  // row_shr:2
    WAVE_MAX_F64_STEP(best, 0x114);  // row_shr:4
    WAVE_MAX_F64_STEP(best, 0x118);  // row_shr:8
    WAVE_MAX_F64_STEP(best, 0x142);  // row_bcast:15
    WAVE_MAX_F64_STEP(best, 0x143);  // row_bcast:31

    const int buf = it & 1;  // double-buffered slots: 1 barrier/iter
    if ((t & 63) == 63) red[buf][t >> 6] = best;
    __syncthreads();

    const double c = fmax(fmax(red[buf][0], red[buf][1]),
                          fmax(red[buf][2], red[buf][3]));
    const u32 widx = ~key_lo(c);  // low word = ~idx

    w = sp[widx];  // broadcast read (same address all lanes)
    lx = w.x; ly = w.y; lz = w.z;

    // off-critical-path register history update (4x cmp+cndmask, no VMEM)
    h0 = (it == t)   ? (int)widx : h0;
    h1 = (it == it1) ? (int)widx : h1;
    h2 = (it == it2) ? (int)widx : h2;
    h3 = (it == it3) ? (int)widx : h3;
  }

  // Epilogue: 4 coalesced stores per thread write all M winner indices.
  const int base = b * MPTS;
  const int goff = b * NPTS;
  gidx[base + t]       = goff + h0;
  gidx[base + 256 + t] = goff + h1;
  gidx[base + 512 + t] = goff + h2;
  gidx[base + 768 + t] = goff + h3;
}

// ------------- Kernel 2: k=1 NN + gather-dependent assembly ----------------
// B*32 blocks x 256 threads.
// Phase 1 (nn): 128 hr points/block, 2 threads per point splitting the
// M=1024 lr points in half; packed fp32; u64-key argmin (tie -> smallest j,
// matches np.argmin) via v_min_f64; pair combine via shfl_xor(1). nng stays
// in LDS (snn).
// Phase 2: only the FPS/NN-dependent columns remain (out[:,67..133] =
// [x[g] | pos[g]]) — the static columns are written by fps_static_kernel's
// rider blocks. Wave-coalesced: 32 rows per wave, lane-parallel.
__global__ __launch_bounds__(256) void nn_dyn_kernel(
    const float* __restrict__ x, const float* __restrict__ pos,
    const int* __restrict__ gidx, float* __restrict__ out) {
#pragma clang fp contract(off)
  const int b = blockIdx.x >> 5;
  const int chunk = blockIdx.x & 31;
  const int t = threadIdx.x;

  __shared__ float lrx[MPTS], lry[MPTS], lrz[MPTS];
  __shared__ int snn[128];

  for (int j = t; j < MPTS; j += 256) {
    const int g = gidx[b * MPTS + j];
    lrx[j] = pos[3 * g + 0];
    lry[j] = pos[3 * g + 1];
    lrz[j] = pos[3 * g + 2];
  }
  __syncthreads();

  const int r = t >> 1;      // local row 0..127
  const int half = t & 1;
  const int i = b * NPTS + chunk * 128 + r;  // global hr point index
  const float X = pos[3 * i + 0];
  const float Y = pos[3 * i + 1];
  const float Z = pos[3 * i + 2];
  const v2f vX = {X, X}, vY = {Y, Y}, vZ = {Z, Z};

  double best = __longlong_as_double(0x7FEFFFFFFFFFFFFFll);  // +DBL_MAX > all keys
  const int j0 = half * 512;
#pragma unroll 4
  for (int s = 0; s < 256; ++s) {
    const int j = j0 + 2 * s;
    const v2f qx = *(const v2f*)&lrx[j];
    const v2f qy = *(const v2f*)&lry[j];
    const v2f qz = *(const v2f*)&lrz[j];
    const v2f dx = vX - qx;
    const v2f dy = vY - qy;
    const v2f dz = vZ - qz;
    const v2f d = (dx * dx + dy * dy) + dz * dz;
    const double p0 = mk_key(d[0], (u32)j);
    const double p1 = mk_key(d[1], (u32)(j + 1));
    best = fmin(best, fmin(p0, p1));
  }
  // pair combine across the two halves (lanes differ only in bit 0)
  const u64 bu = (u64)__double_as_longlong(best);
  const u64 ou = ((u64)(u32)__shfl_xor((int)(bu >> 32), 1, 64) << 32) |
                 (u64)(u32)__shfl_xor((int)(u32)bu, 1, 64);
  best = fmin(best, __longlong_as_double((long long)ou));
  if (half == 0) snn[r] = gidx[b * MPTS + (int)key_lo(best)];
  __syncthreads();

  // ---- dependent assembly: wave-coalesced, 32 rows per wave ----
  const int wid = t >> 6;
  const int lane = t & 63;
  const int rowbase = b * NPTS + chunk * 128;
#pragma unroll 4
  for (int n = 0; n < 32; ++n) {
    const int rr = wid * 32 + n;
    const int ii = rowbase + rr;
    const int g = snn[rr];
    float* o = out + (size_t)ii * 134;
    o[67 + lane] = x[(size_t)g * DIM + lane];    // coalesced row gather
    if (lane < 3) o[131 + lane] = pos[3 * g + lane];
  }
}

// ---------------------------------------------------------------------------
extern "C" void kernel_launch(void* const* d_in, const int* in_sizes, int n_in,
                              void* d_out, int out_size, void* d_ws, size_t ws_size,
                              hipStream_t stream) {
  const float* x = (const float*)d_in[0];
  const float* pos = (const float*)d_in[1];

  int* gidx = (int*)d_ws;  // [B*M] global indices of sampled points

  float* out = (float*)d_out;

  fps_static_kernel<<<BATCH + SA_BLOCKS, 256, 0, stream>>>(pos, x, gidx, out);
  nn_dyn_kernel<<<BATCH * 32, 256, 0, stream>>>(x, pos, gidx, out);
}